// Round 8
// baseline (680.546 us; speedup 1.0000x reference)
//
#include <hip/hip_runtime.h>

// LightGCN on MI355X (gfx950).
// N = 150000 nodes, d = 64, nnz = 6.4M edges, 3 layers, 4096 queries.
// Pipeline: direct-atomic row-bin scatter (16 edges in flight/thread, padded
// cursors) -> per-bin LDS sort -> wave-per-row gather SpMM on bf16 table
// (layers 1-2 full, layer 3 fused to query rows only, accumulated in f32).

constexpr int D = 64;
constexpr int RB = 64;            // rows per bin
constexpr int BCAP = 4096;        // fixed region capacity per bin (lambda=2731, +26 sigma)
constexpr int EPT = 16;           // edges per thread in bin_scatter
constexpr int CHUNK = 256 * EPT;  // edges per binning workgroup
constexpr int CPAD = 16;          // cursor padding: one counter per 64B line

__device__ __forceinline__ float bflo(unsigned u) { return __uint_as_float(u << 16); }
__device__ __forceinline__ float bfhi(unsigned u) { return __uint_as_float(u & 0xFFFF0000u); }
__device__ __forceinline__ float bf1(ushort u) { return __uint_as_float((unsigned)u << 16); }
__device__ __forceinline__ unsigned bfpack(float f0, float f1) {
    unsigned u0 = __float_as_uint(f0), u1 = __float_as_uint(f1);
    u0 = (u0 + 0x7FFFu + ((u0 >> 16) & 1u)) >> 16;   // round-to-nearest-even
    u1 = (u1 + 0x7FFFu + ((u1 >> 16) & 1u)) >> 16;
    return u0 | (u1 << 16);
}

// ---- pack e0 = [user_emb; item_emb] into bf16 table ----
__global__ __launch_bounds__(256) void pack_e0(const float4* __restrict__ u4,
                                               const float4* __restrict__ i4,
                                               uint2* __restrict__ ebf2,
                                               long long nU4, long long total4) {
    long long t = (long long)blockIdx.x * blockDim.x + threadIdx.x;
    if (t >= total4) return;
    float4 v = (t < nU4) ? u4[t] : i4[t - nU4];
    ebf2[t] = make_uint2(bfpack(v.x, v.y), bfpack(v.z, v.w));
}

// ---- init query accumulators with layer-0 embeddings (f32 inputs, exact) ----
__global__ __launch_bounds__(64) void gather_init(const float* __restrict__ ue,
                                                  const float* __restrict__ ie,
                                                  const int* __restrict__ uidx,
                                                  const int* __restrict__ iidx,
                                                  float* __restrict__ accU,
                                                  float* __restrict__ accI) {
    int j = blockIdx.x;
    int lane = threadIdx.x;
    accU[(size_t)j * D + lane] = ue[(size_t)uidx[j] * D + lane];
    accI[(size_t)j * D + lane] = ie[(size_t)iidx[j] * D + lane];
}

// ---- direct-atomic scatter into fixed-capacity bin regions ----
// No LDS, no histogram: 16 edges fully in registers per thread, 16 independent
// {global atomicAdd -> store} chains in flight. Cursors padded to 64B lines.
// packed .x: bits[23:18] = row-in-bin, bits[17:0] = col ; .y = weight bits
__global__ __launch_bounds__(256) void bin_scatter(const int2* __restrict__ idx2,
                                                   const float* __restrict__ adj,
                                                   int* __restrict__ cursor,
                                                   int2* __restrict__ binned,
                                                   long long nnz) {
    long long g0 = (long long)blockIdx.x * CHUNK + (long long)threadIdx.x * EPT;
    if (g0 + EPT <= nnz) {
        int4 m[EPT / 2];
        float4 w[EPT / 4];
        #pragma unroll
        for (int k = 0; k < EPT / 2; ++k) m[k] = *(const int4*)(idx2 + g0 + 2 * k);
        #pragma unroll
        for (int k = 0; k < EPT / 4; ++k) w[k] = *(const float4*)(adj + g0 + 4 * k);
        int pos[EPT], bin[EPT];
        #pragma unroll
        for (int k = 0; k < EPT / 2; ++k) {
            bin[2 * k]     = m[k].x >> 6;
            bin[2 * k + 1] = m[k].z >> 6;
        }
        #pragma unroll
        for (int k = 0; k < EPT; ++k)
            pos[k] = atomicAdd(&cursor[bin[k] * CPAD], 1);    // 16 in flight
        #pragma unroll
        for (int k = 0; k < EPT / 2; ++k) {
            int p0 = pos[2 * k], p1 = pos[2 * k + 1];
            if (p0 < BCAP)
                binned[(size_t)bin[2 * k] * BCAP + p0] =
                    make_int2(((m[k].x & 63) << 18) | m[k].y,
                              __float_as_int(((const float*)w)[2 * k]));
            if (p1 < BCAP)
                binned[(size_t)bin[2 * k + 1] * BCAP + p1] =
                    make_int2(((m[k].z & 63) << 18) | m[k].w,
                              __float_as_int(((const float*)w)[2 * k + 1]));
        }
    } else {
        for (int i = 0; i < EPT; ++i) {
            long long g = g0 + i;
            if (g < nnz) {
                int2 rc = idx2[g];
                int b = rc.x >> 6;
                int pos = atomicAdd(&cursor[b * CPAD], 1);
                if (pos < BCAP)
                    binned[(size_t)b * BCAP + pos] =
                        make_int2(((rc.x & 63) << 18) | rc.y, __float_as_int(adj[g]));
            }
        }
    }
}

// ---- per-bin LDS sort: bin region -> row-sorted region + per-row (start,end) ----
__global__ __launch_bounds__(256) void bin_sort(int2* __restrict__ binned,
                                                const int* __restrict__ cursor,
                                                int2* __restrict__ row_se,
                                                int N) {
    __shared__ int2 buf[BCAP];    // 32 KB
    __shared__ int h[RB];
    __shared__ int lcur[RB];
    int b = blockIdx.x, tid = threadIdx.x;
    size_t bbase = (size_t)b * BCAP;
    int len = cursor[b * CPAD];
    if (len > BCAP) len = BCAP;
    for (int i = tid; i < len; i += 256) buf[i] = binned[bbase + i];
    if (tid < RB) h[tid] = 0;
    __syncthreads();
    for (int i = tid; i < len; i += 256) atomicAdd(&h[(buf[i].x >> 18) & 63], 1);
    __syncthreads();
    if (tid < RB) {                          // wave 0: 64-wide exclusive scan
        int v = h[tid];
        int incl = v;
        #pragma unroll
        for (int off = 1; off < RB; off <<= 1) {
            int t = __shfl_up(incl, off, 64);
            if (tid >= off) incl += t;
        }
        int excl = incl - v;
        lcur[tid] = excl;
        int row = b * RB + tid;
        if (row < N) row_se[row] = make_int2((int)bbase + excl, (int)bbase + excl + v);
    }
    __syncthreads();
    for (int i = tid; i < len; i += 256) {
        int2 p = buf[i];
        int rb = (p.x >> 18) & 63;
        int pos = atomicAdd(&lcur[rb], 1);
        binned[bbase + pos] = make_int2(p.x & 0x3FFFF, p.y);   // strip rb
    }
}

// ---- SpMM (full): wave per row, 8 edges in flight, bf16 gathers, f32 acc ----
__global__ __launch_bounds__(256) void spmm_bf16(const int2* __restrict__ csr,
                                                 const int2* __restrict__ row_se,
                                                 const ushort* __restrict__ ebf,
                                                 ushort* __restrict__ ebf_next,
                                                 int N) {
    int tid = threadIdx.x;
    int row = blockIdx.x * 4 + (tid >> 6);
    if (row >= N) return;
    int lane = tid & 63, eg = lane >> 3, sub = lane & 7;
    int2 se = row_se[row];
    int s = se.x, len = se.y - se.x;
    float a0 = 0, a1 = 0, a2 = 0, a3 = 0, a4 = 0, a5 = 0, a6 = 0, a7 = 0;
    #pragma unroll 2
    for (int i = eg; i < len; i += 8) {
        int2 cw = csr[s + i];
        float w = __int_as_float(cw.y);
        uint4 v = *(const uint4*)(ebf + (size_t)cw.x * D + sub * 8);   // 16B = 8 bf16
        a0 += w * bflo(v.x); a1 += w * bfhi(v.x);
        a2 += w * bflo(v.y); a3 += w * bfhi(v.y);
        a4 += w * bflo(v.z); a5 += w * bfhi(v.z);
        a6 += w * bflo(v.w); a7 += w * bfhi(v.w);
    }
    #pragma unroll
    for (int off = 8; off < 64; off <<= 1) {
        a0 += __shfl_xor(a0, off, 64); a1 += __shfl_xor(a1, off, 64);
        a2 += __shfl_xor(a2, off, 64); a3 += __shfl_xor(a3, off, 64);
        a4 += __shfl_xor(a4, off, 64); a5 += __shfl_xor(a5, off, 64);
        a6 += __shfl_xor(a6, off, 64); a7 += __shfl_xor(a7, off, 64);
    }
    if (eg == 0) {
        uint4 pk = make_uint4(bfpack(a0, a1), bfpack(a2, a3), bfpack(a4, a5), bfpack(a6, a7));
        *(uint4*)(ebf_next + (size_t)row * D + sub * 8) = pk;
    }
}

// ---- SpMM (layer 3, fused): query rows only, accumulate f32 into accU/accI ----
__global__ __launch_bounds__(256) void spmm_query(const int2* __restrict__ csr,
                                                  const int2* __restrict__ row_se,
                                                  const ushort* __restrict__ ebf,
                                                  const int* __restrict__ uidx,
                                                  const int* __restrict__ iidx,
                                                  float* __restrict__ accU,
                                                  float* __restrict__ accI,
                                                  int n_users, int nq) {
    int tid = threadIdx.x;
    int vq = blockIdx.x * 4 + (tid >> 6);
    if (vq >= 2 * nq) return;
    int lane = tid & 63, eg = lane >> 3, sub = lane & 7;
    bool isU = vq < nq;
    int j = isU ? vq : vq - nq;
    int row = isU ? uidx[j] : n_users + iidx[j];
    int2 se = row_se[row];
    int s = se.x, len = se.y - se.x;
    float a0 = 0, a1 = 0, a2 = 0, a3 = 0, a4 = 0, a5 = 0, a6 = 0, a7 = 0;
    #pragma unroll 2
    for (int i = eg; i < len; i += 8) {
        int2 cw = csr[s + i];
        float w = __int_as_float(cw.y);
        uint4 v = *(const uint4*)(ebf + (size_t)cw.x * D + sub * 8);
        a0 += w * bflo(v.x); a1 += w * bfhi(v.x);
        a2 += w * bflo(v.y); a3 += w * bfhi(v.y);
        a4 += w * bflo(v.z); a5 += w * bfhi(v.z);
        a6 += w * bflo(v.w); a7 += w * bfhi(v.w);
    }
    #pragma unroll
    for (int off = 8; off < 64; off <<= 1) {
        a0 += __shfl_xor(a0, off, 64); a1 += __shfl_xor(a1, off, 64);
        a2 += __shfl_xor(a2, off, 64); a3 += __shfl_xor(a3, off, 64);
        a4 += __shfl_xor(a4, off, 64); a5 += __shfl_xor(a5, off, 64);
        a6 += __shfl_xor(a6, off, 64); a7 += __shfl_xor(a7, off, 64);
    }
    if (eg == 0) {
        float* acc = (isU ? accU : accI) + (size_t)j * D + sub * 8;
        float4* f4 = (float4*)acc;
        float4 c0 = f4[0], c1 = f4[1];
        f4[0] = make_float4(c0.x + a0, c0.y + a1, c0.z + a2, c0.w + a3);
        f4[1] = make_float4(c1.x + a4, c1.y + a5, c1.z + a6, c1.w + a7);
    }
}

// ---- fold one layer's gathered rows (bf16 table) into the f32 accumulators ----
__global__ __launch_bounds__(64) void gather_acc(const ushort* __restrict__ e,
                                                 const int* __restrict__ uidx,
                                                 const int* __restrict__ iidx,
                                                 float* __restrict__ accU,
                                                 float* __restrict__ accI,
                                                 int n_users) {
    int j = blockIdx.x;
    int lane = threadIdx.x;
    accU[(size_t)j * D + lane] += bf1(e[(size_t)uidx[j] * D + lane]);
    accI[(size_t)j * D + lane] += bf1(e[((size_t)n_users + iidx[j]) * D + lane]);
}

// ---- final dot: out[j] = dot(accU[j]/4, accI[j]/4) ----
__global__ __launch_bounds__(64) void final_dot(const float* __restrict__ accU,
                                                const float* __restrict__ accI,
                                                float* __restrict__ out) {
    int j = blockIdx.x;
    int lane = threadIdx.x;
    float p = accU[(size_t)j * D + lane] * accI[(size_t)j * D + lane];
    #pragma unroll
    for (int off = 32; off > 0; off >>= 1) p += __shfl_down(p, off);
    if (lane == 0) out[j] = p * (1.0f / 16.0f);
}

extern "C" void kernel_launch(void* const* d_in, const int* in_sizes, int n_in,
                              void* d_out, int out_size, void* d_ws, size_t ws_size,
                              hipStream_t stream) {
    const float* user_emb = (const float*)d_in[0];
    const float* item_emb = (const float*)d_in[1];
    const float* adj_data = (const float*)d_in[2];
    const int* adj_indices = (const int*)d_in[3];
    const int* user_idx = (const int*)d_in[4];
    const int* item_idx = (const int*)d_in[5];
    float* out = (float*)d_out;

    const int n_users = in_sizes[0] / D;
    const int n_items = in_sizes[1] / D;
    const long long nnz = in_sizes[2];
    const int N = n_users + n_items;
    const int nq = in_sizes[4];
    const int NB = (N + RB - 1) / RB;

    // ---- workspace layout (~119 MB) ----
    char* p = (char*)d_ws;
    auto alloc = [&](size_t bytes) { char* q = p; p += (bytes + 255) & ~(size_t)255; return q; };
    ushort* ebf0 = (ushort*)alloc((size_t)N * D * sizeof(ushort));   // bf16 table ping
    ushort* ebf1 = (ushort*)alloc((size_t)N * D * sizeof(ushort));   // bf16 table pong
    float* accU = (float*)alloc((size_t)nq * D * sizeof(float));
    float* accI = (float*)alloc((size_t)nq * D * sizeof(float));
    int2* binned = (int2*)alloc((size_t)NB * BCAP * sizeof(int2));   // fixed bin regions
    int* cursor = (int*)alloc((size_t)NB * CPAD * sizeof(int));      // line-padded
    int2* row_se = (int2*)alloc((size_t)N * sizeof(int2));

    const int2* idx2 = (const int2*)adj_indices;
    const int nChunks = (int)((nnz + CHUNK - 1) / CHUNK);

    // ---- e0 (bf16) = concat(user_emb, item_emb) ----
    {
        long long total4 = (long long)N * (D / 4);
        long long nU4 = (long long)n_users * (D / 4);
        pack_e0<<<(int)((total4 + 255) / 256), 256, 0, stream>>>(
            (const float4*)user_emb, (const float4*)item_emb, (uint2*)ebf0, nU4, total4);
    }
    gather_init<<<nq, 64, 0, stream>>>(user_emb, item_emb, user_idx, item_idx, accU, accI);

    // ---- build row-sorted bin regions ----
    hipMemsetAsync(cursor, 0, (size_t)NB * CPAD * sizeof(int), stream);
    bin_scatter<<<nChunks, 256, 0, stream>>>(idx2, adj_data, cursor, binned, nnz);
    bin_sort<<<NB, 256, 0, stream>>>(binned, cursor, row_se, N);

    // ---- layers 1-2: full SpMM + query-row accumulation ----
    ushort* ebc = ebf0;
    ushort* ebn = ebf1;
    const int spmm_blocks = (N + 3) / 4;
    for (int layer = 0; layer < 2; ++layer) {
        spmm_bf16<<<spmm_blocks, 256, 0, stream>>>(binned, row_se, ebc, ebn, N);
        gather_acc<<<nq, 64, 0, stream>>>(ebn, user_idx, item_idx, accU, accI, n_users);
        ushort* t = ebc; ebc = ebn; ebn = t;
    }

    // ---- layer 3 fused: SpMM restricted to the 8192 query rows, f32 accumulate ----
    spmm_query<<<(2 * nq + 3) / 4, 256, 0, stream>>>(binned, row_se, ebc, user_idx, item_idx,
                                                     accU, accI, n_users, nq);

    final_dot<<<nq, 64, 0, stream>>>(accU, accI, out);
}

// Round 9
// 394.655 us; speedup vs baseline: 1.7244x; 1.7244x over previous
//
#include <hip/hip_runtime.h>

// LightGCN on MI355X (gfx950).
// N = 150000 nodes, d = 64, nnz = 6.4M edges, 3 layers, 4096 queries.
// Pipeline: LDS-reservation row-bin scatter (16-deep ILP, CHUNK=4096 for
// occupancy) -> per-bin LDS sort -> wave-per-row gather SpMM on bf16 table
// with dual accumulator banks (layers 1-2 full, layer 3 fused to query rows).

constexpr int D = 64;
constexpr int RB = 64;            // rows per bin
constexpr int BCAP = 4096;        // fixed region capacity per bin (lambda=2731, +26 sigma)
constexpr int EPT = 16;           // edges per thread in bin_scatter
constexpr int CHUNK = 256 * EPT;  // 4096 edges per binning workgroup -> ~6 wg/CU

__device__ __forceinline__ float bflo(unsigned u) { return __uint_as_float(u << 16); }
__device__ __forceinline__ float bfhi(unsigned u) { return __uint_as_float(u & 0xFFFF0000u); }
__device__ __forceinline__ float bf1(ushort u) { return __uint_as_float((unsigned)u << 16); }
__device__ __forceinline__ unsigned bfpack(float f0, float f1) {
    unsigned u0 = __float_as_uint(f0), u1 = __float_as_uint(f1);
    u0 = (u0 + 0x7FFFu + ((u0 >> 16) & 1u)) >> 16;   // round-to-nearest-even
    u1 = (u1 + 0x7FFFu + ((u1 >> 16) & 1u)) >> 16;
    return u0 | (u1 << 16);
}

// ---- pack e0 = [user_emb; item_emb] into bf16 table ----
__global__ __launch_bounds__(256) void pack_e0(const float4* __restrict__ u4,
                                               const float4* __restrict__ i4,
                                               uint2* __restrict__ ebf2,
                                               long long nU4, long long total4) {
    long long t = (long long)blockIdx.x * blockDim.x + threadIdx.x;
    if (t >= total4) return;
    float4 v = (t < nU4) ? u4[t] : i4[t - nU4];
    ebf2[t] = make_uint2(bfpack(v.x, v.y), bfpack(v.z, v.w));
}

// ---- init query accumulators with layer-0 embeddings (f32 inputs, exact) ----
__global__ __launch_bounds__(64) void gather_init(const float* __restrict__ ue,
                                                  const float* __restrict__ ie,
                                                  const int* __restrict__ uidx,
                                                  const int* __restrict__ iidx,
                                                  float* __restrict__ accU,
                                                  float* __restrict__ accI) {
    int j = blockIdx.x;
    int lane = threadIdx.x;
    accU[(size_t)j * D + lane] = ue[(size_t)uidx[j] * D + lane];
    accI[(size_t)j * D + lane] = ie[(size_t)iidx[j] * D + lane];
}

// ---- LDS-reservation scatter into fixed-capacity bin regions ----
// packed .x: bits[23:18] = row-in-bin, bits[17:0] = col ; .y = weight bits
__global__ __launch_bounds__(256) void bin_scatter(const int2* __restrict__ idx2,
                                                   const float* __restrict__ adj,
                                                   int* __restrict__ cursor,
                                                   int2* __restrict__ binned,
                                                   long long nnz, int NB) {
    extern __shared__ int sh[];
    int* h = sh;            // [NB] local histogram, then local cursor
    int* rbase = sh + NB;   // [NB] bulk-reserved global base
    const int tid = threadIdx.x;
    for (int i = tid; i < NB; i += 256) h[i] = 0;
    __syncthreads();
    const long long base = (long long)blockIdx.x * CHUNK;
    const bool full = (base + CHUNK <= nnz);

    // ---- histogram phase: 16 edges in registers, 16 LDS atomics in flight ----
    if (full) {
        long long g0 = base + (long long)tid * EPT;
        int4 m[EPT / 2];
        #pragma unroll
        for (int k = 0; k < EPT / 2; ++k) m[k] = *(const int4*)(idx2 + g0 + 2 * k);
        #pragma unroll
        for (int k = 0; k < EPT / 2; ++k) {
            atomicAdd(&h[m[k].x >> 6], 1);
            atomicAdd(&h[m[k].z >> 6], 1);
        }
    } else {
        for (int i = tid; i < CHUNK; i += 256) {
            long long g = base + i;
            if (g < nnz) atomicAdd(&h[idx2[g].x >> 6], 1);
        }
    }
    __syncthreads();

    // ---- bulk reservation ----
    for (int i = tid; i < NB; i += 256) {
        int v = h[i];
        rbase[i] = v ? atomicAdd(&cursor[i], v) : 0;
        h[i] = 0;   // reuse as local cursor
    }
    __syncthreads();

    // ---- scatter phase ----
    auto emit = [&](int row, int col, float w) {
        int b = row >> 6;
        int pos = rbase[b] + atomicAdd(&h[b], 1);
        if (pos < BCAP)   // statistically never taken; memory-safety clamp
            binned[(size_t)b * BCAP + pos] =
                make_int2(((row & 63) << 18) | col, __float_as_int(w));
    };
    if (full) {
        long long g0 = base + (long long)tid * EPT;
        int4 m[EPT / 2];
        float4 w[EPT / 4];
        #pragma unroll
        for (int k = 0; k < EPT / 2; ++k) m[k] = *(const int4*)(idx2 + g0 + 2 * k);
        #pragma unroll
        for (int k = 0; k < EPT / 4; ++k) w[k] = *(const float4*)(adj + g0 + 4 * k);
        #pragma unroll
        for (int k = 0; k < EPT / 2; ++k) {
            // edge 2k and 2k+1 of this batch; weight = ((float*)w)[edge]
            emit(m[k].x, m[k].y, ((const float*)w)[2 * k]);
            emit(m[k].z, m[k].w, ((const float*)w)[2 * k + 1]);
        }
    } else {
        for (int i = tid; i < CHUNK; i += 256) {
            long long g = base + i;
            if (g < nnz) {
                int2 rc = idx2[g];
                emit(rc.x, rc.y, adj[g]);
            }
        }
    }
}

// ---- per-bin LDS sort: bin region -> row-sorted region + per-row (start,end) ----
__global__ __launch_bounds__(256) void bin_sort(int2* __restrict__ binned,
                                                const int* __restrict__ cursor,
                                                int2* __restrict__ row_se,
                                                int N) {
    __shared__ int2 buf[BCAP];    // 32 KB
    __shared__ int h[RB];
    __shared__ int lcur[RB];
    int b = blockIdx.x, tid = threadIdx.x;
    size_t bbase = (size_t)b * BCAP;
    int len = cursor[b];
    if (len > BCAP) len = BCAP;
    for (int i = tid; i < len; i += 256) buf[i] = binned[bbase + i];
    if (tid < RB) h[tid] = 0;
    __syncthreads();
    for (int i = tid; i < len; i += 256) atomicAdd(&h[(buf[i].x >> 18) & 63], 1);
    __syncthreads();
    if (tid < RB) {                          // wave 0: 64-wide exclusive scan
        int v = h[tid];
        int incl = v;
        #pragma unroll
        for (int off = 1; off < RB; off <<= 1) {
            int t = __shfl_up(incl, off, 64);
            if (tid >= off) incl += t;
        }
        int excl = incl - v;
        lcur[tid] = excl;
        int row = b * RB + tid;
        if (row < N) row_se[row] = make_int2((int)bbase + excl, (int)bbase + excl + v);
    }
    __syncthreads();
    for (int i = tid; i < len; i += 256) {
        int2 p = buf[i];
        int rb = (p.x >> 18) & 63;
        int pos = atomicAdd(&lcur[rb], 1);
        binned[bbase + pos] = make_int2(p.x & 0x3FFFF, p.y);   // strip rb
    }
}

// ---- SpMM (full): wave per row, dual accumulator banks (16 gathers in flight) ----
__global__ __launch_bounds__(256) void spmm_bf16(const int2* __restrict__ csr,
                                                 const int2* __restrict__ row_se,
                                                 const ushort* __restrict__ ebf,
                                                 ushort* __restrict__ ebf_next,
                                                 int N) {
    int tid = threadIdx.x;
    int row = blockIdx.x * 4 + (tid >> 6);
    if (row >= N) return;
    int lane = tid & 63, eg = lane >> 3, sub = lane & 7;
    int2 se = row_se[row];
    int s = se.x, len = se.y - se.x;
    float a0 = 0, a1 = 0, a2 = 0, a3 = 0, a4 = 0, a5 = 0, a6 = 0, a7 = 0;
    float b0 = 0, b1 = 0, b2 = 0, b3 = 0, b4 = 0, b5 = 0, b6 = 0, b7 = 0;
    int i = eg;
    for (; i + 8 < len; i += 16) {           // banks A (i) and B (i+8) independent
        int2 cwA = csr[s + i];
        int2 cwB = csr[s + i + 8];
        float wA = __int_as_float(cwA.y);
        float wB = __int_as_float(cwB.y);
        uint4 vA = *(const uint4*)(ebf + (size_t)cwA.x * D + sub * 8);
        uint4 vB = *(const uint4*)(ebf + (size_t)cwB.x * D + sub * 8);
        a0 += wA * bflo(vA.x); a1 += wA * bfhi(vA.x);
        a2 += wA * bflo(vA.y); a3 += wA * bfhi(vA.y);
        a4 += wA * bflo(vA.z); a5 += wA * bfhi(vA.z);
        a6 += wA * bflo(vA.w); a7 += wA * bfhi(vA.w);
        b0 += wB * bflo(vB.x); b1 += wB * bfhi(vB.x);
        b2 += wB * bflo(vB.y); b3 += wB * bfhi(vB.y);
        b4 += wB * bflo(vB.z); b5 += wB * bfhi(vB.z);
        b6 += wB * bflo(vB.w); b7 += wB * bfhi(vB.w);
    }
    if (i < len) {                           // tail: one more bank-A batch
        int2 cw = csr[s + i];
        float w = __int_as_float(cw.y);
        uint4 v = *(const uint4*)(ebf + (size_t)cw.x * D + sub * 8);
        a0 += w * bflo(v.x); a1 += w * bfhi(v.x);
        a2 += w * bflo(v.y); a3 += w * bfhi(v.y);
        a4 += w * bflo(v.z); a5 += w * bfhi(v.z);
        a6 += w * bflo(v.w); a7 += w * bfhi(v.w);
    }
    a0 += b0; a1 += b1; a2 += b2; a3 += b3;
    a4 += b4; a5 += b5; a6 += b6; a7 += b7;
    #pragma unroll
    for (int off = 8; off < 64; off <<= 1) {
        a0 += __shfl_xor(a0, off, 64); a1 += __shfl_xor(a1, off, 64);
        a2 += __shfl_xor(a2, off, 64); a3 += __shfl_xor(a3, off, 64);
        a4 += __shfl_xor(a4, off, 64); a5 += __shfl_xor(a5, off, 64);
        a6 += __shfl_xor(a6, off, 64); a7 += __shfl_xor(a7, off, 64);
    }
    if (eg == 0) {
        uint4 pk = make_uint4(bfpack(a0, a1), bfpack(a2, a3), bfpack(a4, a5), bfpack(a6, a7));
        *(uint4*)(ebf_next + (size_t)row * D + sub * 8) = pk;
    }
}

// ---- SpMM (layer 3, fused): query rows only, accumulate f32 into accU/accI ----
__global__ __launch_bounds__(256) void spmm_query(const int2* __restrict__ csr,
                                                  const int2* __restrict__ row_se,
                                                  const ushort* __restrict__ ebf,
                                                  const int* __restrict__ uidx,
                                                  const int* __restrict__ iidx,
                                                  float* __restrict__ accU,
                                                  float* __restrict__ accI,
                                                  int n_users, int nq) {
    int tid = threadIdx.x;
    int vq = blockIdx.x * 4 + (tid >> 6);
    if (vq >= 2 * nq) return;
    int lane = tid & 63, eg = lane >> 3, sub = lane & 7;
    bool isU = vq < nq;
    int j = isU ? vq : vq - nq;
    int row = isU ? uidx[j] : n_users + iidx[j];
    int2 se = row_se[row];
    int s = se.x, len = se.y - se.x;
    float a0 = 0, a1 = 0, a2 = 0, a3 = 0, a4 = 0, a5 = 0, a6 = 0, a7 = 0;
    #pragma unroll 2
    for (int i = eg; i < len; i += 8) {
        int2 cw = csr[s + i];
        float w = __int_as_float(cw.y);
        uint4 v = *(const uint4*)(ebf + (size_t)cw.x * D + sub * 8);
        a0 += w * bflo(v.x); a1 += w * bfhi(v.x);
        a2 += w * bflo(v.y); a3 += w * bfhi(v.y);
        a4 += w * bflo(v.z); a5 += w * bfhi(v.z);
        a6 += w * bflo(v.w); a7 += w * bfhi(v.w);
    }
    #pragma unroll
    for (int off = 8; off < 64; off <<= 1) {
        a0 += __shfl_xor(a0, off, 64); a1 += __shfl_xor(a1, off, 64);
        a2 += __shfl_xor(a2, off, 64); a3 += __shfl_xor(a3, off, 64);
        a4 += __shfl_xor(a4, off, 64); a5 += __shfl_xor(a5, off, 64);
        a6 += __shfl_xor(a6, off, 64); a7 += __shfl_xor(a7, off, 64);
    }
    if (eg == 0) {
        float* acc = (isU ? accU : accI) + (size_t)j * D + sub * 8;
        float4* f4 = (float4*)acc;
        float4 c0 = f4[0], c1 = f4[1];
        f4[0] = make_float4(c0.x + a0, c0.y + a1, c0.z + a2, c0.w + a3);
        f4[1] = make_float4(c1.x + a4, c1.y + a5, c1.z + a6, c1.w + a7);
    }
}

// ---- fold one layer's gathered rows (bf16 table) into the f32 accumulators ----
__global__ __launch_bounds__(64) void gather_acc(const ushort* __restrict__ e,
                                                 const int* __restrict__ uidx,
                                                 const int* __restrict__ iidx,
                                                 float* __restrict__ accU,
                                                 float* __restrict__ accI,
                                                 int n_users) {
    int j = blockIdx.x;
    int lane = threadIdx.x;
    accU[(size_t)j * D + lane] += bf1(e[(size_t)uidx[j] * D + lane]);
    accI[(size_t)j * D + lane] += bf1(e[((size_t)n_users + iidx[j]) * D + lane]);
}

// ---- final dot: out[j] = dot(accU[j]/4, accI[j]/4) ----
__global__ __launch_bounds__(64) void final_dot(const float* __restrict__ accU,
                                                const float* __restrict__ accI,
                                                float* __restrict__ out) {
    int j = blockIdx.x;
    int lane = threadIdx.x;
    float p = accU[(size_t)j * D + lane] * accI[(size_t)j * D + lane];
    #pragma unroll
    for (int off = 32; off > 0; off >>= 1) p += __shfl_down(p, off);
    if (lane == 0) out[j] = p * (1.0f / 16.0f);
}

extern "C" void kernel_launch(void* const* d_in, const int* in_sizes, int n_in,
                              void* d_out, int out_size, void* d_ws, size_t ws_size,
                              hipStream_t stream) {
    const float* user_emb = (const float*)d_in[0];
    const float* item_emb = (const float*)d_in[1];
    const float* adj_data = (const float*)d_in[2];
    const int* adj_indices = (const int*)d_in[3];
    const int* user_idx = (const int*)d_in[4];
    const int* item_idx = (const int*)d_in[5];
    float* out = (float*)d_out;

    const int n_users = in_sizes[0] / D;
    const int n_items = in_sizes[1] / D;
    const long long nnz = in_sizes[2];
    const int N = n_users + n_items;
    const int nq = in_sizes[4];
    const int NB = (N + RB - 1) / RB;

    // ---- workspace layout (~118 MB) ----
    char* p = (char*)d_ws;
    auto alloc = [&](size_t bytes) { char* q = p; p += (bytes + 255) & ~(size_t)255; return q; };
    ushort* ebf0 = (ushort*)alloc((size_t)N * D * sizeof(ushort));   // bf16 table ping
    ushort* ebf1 = (ushort*)alloc((size_t)N * D * sizeof(ushort));   // bf16 table pong
    float* accU = (float*)alloc((size_t)nq * D * sizeof(float));
    float* accI = (float*)alloc((size_t)nq * D * sizeof(float));
    int2* binned = (int2*)alloc((size_t)NB * BCAP * sizeof(int2));   // fixed bin regions
    int* cursor = (int*)alloc((size_t)NB * sizeof(int));
    int2* row_se = (int2*)alloc((size_t)N * sizeof(int2));

    const int2* idx2 = (const int2*)adj_indices;
    const int nChunks = (int)((nnz + CHUNK - 1) / CHUNK);
    const size_t sh_bytes = (size_t)2 * NB * sizeof(int);   // 18.75 KB -> up to 8 wg/CU

    // ---- e0 (bf16) = concat(user_emb, item_emb) ----
    {
        long long total4 = (long long)N * (D / 4);
        long long nU4 = (long long)n_users * (D / 4);
        pack_e0<<<(int)((total4 + 255) / 256), 256, 0, stream>>>(
            (const float4*)user_emb, (const float4*)item_emb, (uint2*)ebf0, nU4, total4);
    }
    gather_init<<<nq, 64, 0, stream>>>(user_emb, item_emb, user_idx, item_idx, accU, accI);

    // ---- build row-sorted bin regions ----
    hipMemsetAsync(cursor, 0, (size_t)NB * sizeof(int), stream);
    bin_scatter<<<nChunks, 256, sh_bytes, stream>>>(idx2, adj_data, cursor, binned, nnz, NB);
    bin_sort<<<NB, 256, 0, stream>>>(binned, cursor, row_se, N);

    // ---- layers 1-2: full SpMM + query-row accumulation ----
    ushort* ebc = ebf0;
    ushort* ebn = ebf1;
    const int spmm_blocks = (N + 3) / 4;
    for (int layer = 0; layer < 2; ++layer) {
        spmm_bf16<<<spmm_blocks, 256, 0, stream>>>(binned, row_se, ebc, ebn, N);
        gather_acc<<<nq, 64, 0, stream>>>(ebn, user_idx, item_idx, accU, accI, n_users);
        ushort* t = ebc; ebc = ebn; ebn = t;
    }

    // ---- layer 3 fused: SpMM restricted to the 8192 query rows, f32 accumulate ----
    spmm_query<<<(2 * nq + 3) / 4, 256, 0, stream>>>(binned, row_se, ebc, user_idx, item_idx,
                                                     accU, accI, n_users, nq);

    final_dot<<<nq, 64, 0, stream>>>(accU, accI, out);
}

// Round 10
// 371.771 us; speedup vs baseline: 1.8306x; 1.0616x over previous
//
#include <hip/hip_runtime.h>

// LightGCN on MI355X (gfx950).
// N = 150000 nodes, d = 64, nnz = 6.4M edges, 3 layers, 4096 queries.
// Pipeline: TWO-LEVEL radix scatter (super-bins of 4096 rows -> fine bins of
// 64 rows; both phases write long contiguous runs, ~full-line DRAM writes)
// -> per-bin LDS sort -> wave-per-row gather SpMM on bf16 table
// (layers 1-2 full, layer 3 fused to query rows, f32 accumulate).

constexpr int D = 64;
constexpr int RB = 64;            // rows per fine bin
constexpr int BCAP = 3072;        // fine-bin capacity (lambda=2731, +6.5 sigma)
constexpr int SRB = 4096;         // rows per super-bin
constexpr int SCAP = 180224;      // super-bin capacity = 22*8192 (lambda~173K, +17 sigma)
constexpr int SCHUNK = 8192;      // A2 edges per workgroup
constexpr int CPS = SCAP / SCHUNK; // chunks per super-bin = 22
constexpr int CHUNK = 8192;       // A1 edges per workgroup (32/thread)
constexpr int SB_MAX = 64;        // super-bin LDS capacity (N <= 262144)

__device__ __forceinline__ float bflo(unsigned u) { return __uint_as_float(u << 16); }
__device__ __forceinline__ float bfhi(unsigned u) { return __uint_as_float(u & 0xFFFF0000u); }
__device__ __forceinline__ float bf1(ushort u) { return __uint_as_float((unsigned)u << 16); }
__device__ __forceinline__ unsigned bfpack(float f0, float f1) {
    unsigned u0 = __float_as_uint(f0), u1 = __float_as_uint(f1);
    u0 = (u0 + 0x7FFFu + ((u0 >> 16) & 1u)) >> 16;   // round-to-nearest-even
    u1 = (u1 + 0x7FFFu + ((u1 >> 16) & 1u)) >> 16;
    return u0 | (u1 << 16);
}

// ---- pack e0 = [user_emb; item_emb] into bf16 table ----
__global__ __launch_bounds__(256) void pack_e0(const float4* __restrict__ u4,
                                               const float4* __restrict__ i4,
                                               uint2* __restrict__ ebf2,
                                               long long nU4, long long total4) {
    long long t = (long long)blockIdx.x * blockDim.x + threadIdx.x;
    if (t >= total4) return;
    float4 v = (t < nU4) ? u4[t] : i4[t - nU4];
    ebf2[t] = make_uint2(bfpack(v.x, v.y), bfpack(v.z, v.w));
}

// ---- init query accumulators with layer-0 embeddings (f32 inputs, exact) ----
__global__ __launch_bounds__(64) void gather_init(const float* __restrict__ ue,
                                                  const float* __restrict__ ie,
                                                  const int* __restrict__ uidx,
                                                  const int* __restrict__ iidx,
                                                  float* __restrict__ accU,
                                                  float* __restrict__ accI) {
    int j = blockIdx.x;
    int lane = threadIdx.x;
    accU[(size_t)j * D + lane] = ue[(size_t)uidx[j] * D + lane];
    accI[(size_t)j * D + lane] = ie[(size_t)iidx[j] * D + lane];
}

// ---- A1: scatter edges into 37 super-bin regions (runs ~221 edges = 1.77KB) ----
// packed .x: bits[29:18] = row-in-super (12b), bits[17:0] = col ; .y = weight
__global__ __launch_bounds__(256) void scatter_super(const int2* __restrict__ idx2,
                                                     const float* __restrict__ adj,
                                                     int* __restrict__ scur,
                                                     int2* __restrict__ sbinned,
                                                     long long nnz, int nsup) {
    __shared__ int h[SB_MAX];
    __shared__ int rbase[SB_MAX];
    const int tid = threadIdx.x;
    if (tid < nsup) h[tid] = 0;
    __syncthreads();
    const long long base = (long long)blockIdx.x * CHUNK;
    const bool full = (base + CHUNK <= nnz);

    if (full) {
        #pragma unroll
        for (int bb = 0; bb < 2; ++bb) {
            long long g0 = base + bb * 4096 + (long long)tid * 16;
            int4 m[8];
            #pragma unroll
            for (int k = 0; k < 8; ++k) m[k] = *(const int4*)(idx2 + g0 + 2 * k);
            #pragma unroll
            for (int k = 0; k < 8; ++k) {
                atomicAdd(&h[m[k].x >> 12], 1);
                atomicAdd(&h[m[k].z >> 12], 1);
            }
        }
    } else {
        for (int i = tid; i < CHUNK; i += 256) {
            long long g = base + i;
            if (g < nnz) atomicAdd(&h[idx2[g].x >> 12], 1);
        }
    }
    __syncthreads();
    if (tid < nsup) {
        int v = h[tid];
        rbase[tid] = v ? atomicAdd(&scur[tid], v) : 0;
        h[tid] = 0;
    }
    __syncthreads();
    auto emit = [&](int row, int col, float w) {
        int s = row >> 12;
        int pos = rbase[s] + atomicAdd(&h[s], 1);
        if (pos < SCAP)   // statistically never taken; memory-safety clamp
            sbinned[(size_t)s * SCAP + pos] =
                make_int2(((row & (SRB - 1)) << 18) | col, __float_as_int(w));
    };
    if (full) {
        #pragma unroll
        for (int bb = 0; bb < 2; ++bb) {
            long long g0 = base + bb * 4096 + (long long)tid * 16;
            int4 m[8];
            float4 w[4];
            #pragma unroll
            for (int k = 0; k < 8; ++k) m[k] = *(const int4*)(idx2 + g0 + 2 * k);
            #pragma unroll
            for (int k = 0; k < 4; ++k) w[k] = *(const float4*)(adj + g0 + 4 * k);
            #pragma unroll
            for (int k = 0; k < 8; ++k) {
                emit(m[k].x, m[k].y, ((const float*)w)[2 * k]);
                emit(m[k].z, m[k].w, ((const float*)w)[2 * k + 1]);
            }
        }
    } else {
        for (int i = tid; i < CHUNK; i += 256) {
            long long g = base + i;
            if (g < nnz) {
                int2 rc = idx2[g];
                emit(rc.x, rc.y, adj[g]);
            }
        }
    }
}

// ---- A2: re-scatter each super-bin into its 64 fine bins (runs ~128 = 1KB) ----
// fine bin id (global) = s*64 + (row_in_super>>6) = row>>6.
// output .x: bits[23:18] = row-in-bin, bits[17:0] = col (bin_sort format)
__global__ __launch_bounds__(256) void scatter_fine(const int2* __restrict__ sbinned,
                                                    const int* __restrict__ scount,
                                                    int* __restrict__ cursor,
                                                    int2* __restrict__ binned) {
    __shared__ int h[64];
    __shared__ int rbase[64];
    const int tid = threadIdx.x;
    const int s = blockIdx.x / CPS;
    const int c = blockIdx.x % CPS;
    int len = scount[s];
    if (len > SCAP) len = SCAP;
    const int begin = c * SCHUNK;
    const int end = min(begin + SCHUNK, len);
    if (begin >= end) return;   // workgroup-uniform exit
    if (tid < 64) h[tid] = 0;
    __syncthreads();
    const int2* src = sbinned + (size_t)s * SCAP;
    const bool full = (end - begin == SCHUNK);

    if (full) {
        #pragma unroll
        for (int bb = 0; bb < 2; ++bb) {
            int g0 = begin + bb * 4096 + tid * 16;
            int4 m[8];
            #pragma unroll
            for (int k = 0; k < 8; ++k) m[k] = *(const int4*)(src + g0 + 2 * k);
            #pragma unroll
            for (int k = 0; k < 8; ++k) {
                atomicAdd(&h[(m[k].x >> 24) & 63], 1);
                atomicAdd(&h[(m[k].z >> 24) & 63], 1);
            }
        }
    } else {
        for (int i = begin + tid; i < end; i += 256)
            atomicAdd(&h[(src[i].x >> 24) & 63], 1);
    }
    __syncthreads();
    if (tid < 64) {
        int v = h[tid];
        rbase[tid] = v ? atomicAdd(&cursor[s * 64 + tid], v) : 0;
        h[tid] = 0;
    }
    __syncthreads();
    auto emit = [&](int x, int wbits) {
        int f = (x >> 24) & 63;
        int pos = rbase[f] + atomicAdd(&h[f], 1);
        if (pos < BCAP)   // statistically never taken; memory-safety clamp
            binned[(size_t)(s * 64 + f) * BCAP + pos] = make_int2(x & 0xFFFFFF, wbits);
    };
    if (full) {
        #pragma unroll
        for (int bb = 0; bb < 2; ++bb) {
            int g0 = begin + bb * 4096 + tid * 16;
            int4 m[8];
            #pragma unroll
            for (int k = 0; k < 8; ++k) m[k] = *(const int4*)(src + g0 + 2 * k);
            #pragma unroll
            for (int k = 0; k < 8; ++k) {
                emit(m[k].x, m[k].y);
                emit(m[k].z, m[k].w);
            }
        }
    } else {
        for (int i = begin + tid; i < end; i += 256) {
            int2 e = src[i];
            emit(e.x, e.y);
        }
    }
}

// ---- per-bin LDS sort: bin region -> row-sorted region + per-row (start,end) ----
__global__ __launch_bounds__(256) void bin_sort(int2* __restrict__ binned,
                                                const int* __restrict__ cursor,
                                                int2* __restrict__ row_se,
                                                int N) {
    __shared__ int2 buf[BCAP];    // 24 KB
    __shared__ int h[RB];
    __shared__ int lcur[RB];
    int b = blockIdx.x, tid = threadIdx.x;
    size_t bbase = (size_t)b * BCAP;
    int len = cursor[b];
    if (len > BCAP) len = BCAP;
    for (int i = tid; i < len; i += 256) buf[i] = binned[bbase + i];
    if (tid < RB) h[tid] = 0;
    __syncthreads();
    for (int i = tid; i < len; i += 256) atomicAdd(&h[(buf[i].x >> 18) & 63], 1);
    __syncthreads();
    if (tid < RB) {                          // wave 0: 64-wide exclusive scan
        int v = h[tid];
        int incl = v;
        #pragma unroll
        for (int off = 1; off < RB; off <<= 1) {
            int t = __shfl_up(incl, off, 64);
            if (tid >= off) incl += t;
        }
        int excl = incl - v;
        lcur[tid] = excl;
        int row = b * RB + tid;
        if (row < N) row_se[row] = make_int2((int)bbase + excl, (int)bbase + excl + v);
    }
    __syncthreads();
    for (int i = tid; i < len; i += 256) {
        int2 p = buf[i];
        int rb = (p.x >> 18) & 63;
        int pos = atomicAdd(&lcur[rb], 1);
        binned[bbase + pos] = make_int2(p.x & 0x3FFFF, p.y);   // strip rb
    }
}

// ---- SpMM (full): wave per row, 8 edges in flight, bf16 gathers, f32 acc ----
__global__ __launch_bounds__(256) void spmm_bf16(const int2* __restrict__ csr,
                                                 const int2* __restrict__ row_se,
                                                 const ushort* __restrict__ ebf,
                                                 ushort* __restrict__ ebf_next,
                                                 int N) {
    int tid = threadIdx.x;
    int row = blockIdx.x * 4 + (tid >> 6);
    if (row >= N) return;
    int lane = tid & 63, eg = lane >> 3, sub = lane & 7;
    int2 se = row_se[row];
    int s = se.x, len = se.y - se.x;
    float a0 = 0, a1 = 0, a2 = 0, a3 = 0, a4 = 0, a5 = 0, a6 = 0, a7 = 0;
    #pragma unroll 2
    for (int i = eg; i < len; i += 8) {
        int2 cw = csr[s + i];
        float w = __int_as_float(cw.y);
        uint4 v = *(const uint4*)(ebf + (size_t)cw.x * D + sub * 8);   // 16B = 8 bf16
        a0 += w * bflo(v.x); a1 += w * bfhi(v.x);
        a2 += w * bflo(v.y); a3 += w * bfhi(v.y);
        a4 += w * bflo(v.z); a5 += w * bfhi(v.z);
        a6 += w * bflo(v.w); a7 += w * bfhi(v.w);
    }
    #pragma unroll
    for (int off = 8; off < 64; off <<= 1) {
        a0 += __shfl_xor(a0, off, 64); a1 += __shfl_xor(a1, off, 64);
        a2 += __shfl_xor(a2, off, 64); a3 += __shfl_xor(a3, off, 64);
        a4 += __shfl_xor(a4, off, 64); a5 += __shfl_xor(a5, off, 64);
        a6 += __shfl_xor(a6, off, 64); a7 += __shfl_xor(a7, off, 64);
    }
    if (eg == 0) {
        uint4 pk = make_uint4(bfpack(a0, a1), bfpack(a2, a3), bfpack(a4, a5), bfpack(a6, a7));
        *(uint4*)(ebf_next + (size_t)row * D + sub * 8) = pk;
    }
}

// ---- SpMM (layer 3, fused): query rows only, accumulate f32 into accU/accI ----
__global__ __launch_bounds__(256) void spmm_query(const int2* __restrict__ csr,
                                                  const int2* __restrict__ row_se,
                                                  const ushort* __restrict__ ebf,
                                                  const int* __restrict__ uidx,
                                                  const int* __restrict__ iidx,
                                                  float* __restrict__ accU,
                                                  float* __restrict__ accI,
                                                  int n_users, int nq) {
    int tid = threadIdx.x;
    int vq = blockIdx.x * 4 + (tid >> 6);
    if (vq >= 2 * nq) return;
    int lane = tid & 63, eg = lane >> 3, sub = lane & 7;
    bool isU = vq < nq;
    int j = isU ? vq : vq - nq;
    int row = isU ? uidx[j] : n_users + iidx[j];
    int2 se = row_se[row];
    int s = se.x, len = se.y - se.x;
    float a0 = 0, a1 = 0, a2 = 0, a3 = 0, a4 = 0, a5 = 0, a6 = 0, a7 = 0;
    #pragma unroll 2
    for (int i = eg; i < len; i += 8) {
        int2 cw = csr[s + i];
        float w = __int_as_float(cw.y);
        uint4 v = *(const uint4*)(ebf + (size_t)cw.x * D + sub * 8);
        a0 += w * bflo(v.x); a1 += w * bfhi(v.x);
        a2 += w * bflo(v.y); a3 += w * bfhi(v.y);
        a4 += w * bflo(v.z); a5 += w * bfhi(v.z);
        a6 += w * bflo(v.w); a7 += w * bfhi(v.w);
    }
    #pragma unroll
    for (int off = 8; off < 64; off <<= 1) {
        a0 += __shfl_xor(a0, off, 64); a1 += __shfl_xor(a1, off, 64);
        a2 += __shfl_xor(a2, off, 64); a3 += __shfl_xor(a3, off, 64);
        a4 += __shfl_xor(a4, off, 64); a5 += __shfl_xor(a5, off, 64);
        a6 += __shfl_xor(a6, off, 64); a7 += __shfl_xor(a7, off, 64);
    }
    if (eg == 0) {
        float* acc = (isU ? accU : accI) + (size_t)j * D + sub * 8;
        float4* f4 = (float4*)acc;
        float4 c0 = f4[0], c1 = f4[1];
        f4[0] = make_float4(c0.x + a0, c0.y + a1, c0.z + a2, c0.w + a3);
        f4[1] = make_float4(c1.x + a4, c1.y + a5, c1.z + a6, c1.w + a7);
    }
}

// ---- fold one layer's gathered rows (bf16 table) into the f32 accumulators ----
__global__ __launch_bounds__(64) void gather_acc(const ushort* __restrict__ e,
                                                 const int* __restrict__ uidx,
                                                 const int* __restrict__ iidx,
                                                 float* __restrict__ accU,
                                                 float* __restrict__ accI,
                                                 int n_users) {
    int j = blockIdx.x;
    int lane = threadIdx.x;
    accU[(size_t)j * D + lane] += bf1(e[(size_t)uidx[j] * D + lane]);
    accI[(size_t)j * D + lane] += bf1(e[((size_t)n_users + iidx[j]) * D + lane]);
}

// ---- final dot: out[j] = dot(accU[j]/4, accI[j]/4) ----
__global__ __launch_bounds__(64) void final_dot(const float* __restrict__ accU,
                                                const float* __restrict__ accI,
                                                float* __restrict__ out) {
    int j = blockIdx.x;
    int lane = threadIdx.x;
    float p = accU[(size_t)j * D + lane] * accI[(size_t)j * D + lane];
    #pragma unroll
    for (int off = 32; off > 0; off >>= 1) p += __shfl_down(p, off);
    if (lane == 0) out[j] = p * (1.0f / 16.0f);
}

extern "C" void kernel_launch(void* const* d_in, const int* in_sizes, int n_in,
                              void* d_out, int out_size, void* d_ws, size_t ws_size,
                              hipStream_t stream) {
    const float* user_emb = (const float*)d_in[0];
    const float* item_emb = (const float*)d_in[1];
    const float* adj_data = (const float*)d_in[2];
    const int* adj_indices = (const int*)d_in[3];
    const int* user_idx = (const int*)d_in[4];
    const int* item_idx = (const int*)d_in[5];
    float* out = (float*)d_out;

    const int n_users = in_sizes[0] / D;
    const int n_items = in_sizes[1] / D;
    const long long nnz = in_sizes[2];
    const int N = n_users + n_items;
    const int nq = in_sizes[4];
    const int NB = (N + RB - 1) / RB;            // 2344 fine bins
    const int nsup = (N + SRB - 1) / SRB;        // 37 super-bins
    const int NBF = nsup * 64;                   // fine-bin slots incl. padding (2368)

    // ---- workspace layout (~130 MB); sbinned ALIASES {ebf1,accU,accI,row_se},
    // all of which are first written only after scatter_fine has consumed it ----
    char* p = (char*)d_ws;
    auto alloc = [&](size_t bytes) { char* q = p; p += (bytes + 255) & ~(size_t)255; return q; };
    ushort* ebf0 = (ushort*)alloc((size_t)N * D * sizeof(ushort));     // 19.2 MB
    int2* binned = (int2*)alloc((size_t)NBF * BCAP * sizeof(int2));    // 58.2 MB
    // union region:
    char* uni = p;
    {
        size_t tail = 0;
        tail += ((size_t)N * D * sizeof(ushort) + 255) & ~(size_t)255;   // ebf1
        tail += 2 * (((size_t)nq * D * sizeof(float) + 255) & ~(size_t)255);
        tail += ((size_t)N * sizeof(int2) + 255) & ~(size_t)255;         // row_se
        size_t sb = ((size_t)nsup * SCAP * sizeof(int2) + 255) & ~(size_t)255;
        p += (sb > tail ? sb : tail);
    }
    int2* sbinned = (int2*)uni;                                        // 53.3 MB (dead after A2)
    char* q = uni;
    auto suballoc = [&](size_t bytes) { char* r = q; q += (bytes + 255) & ~(size_t)255; return r; };
    ushort* ebf1 = (ushort*)suballoc((size_t)N * D * sizeof(ushort));
    float* accU = (float*)suballoc((size_t)nq * D * sizeof(float));
    float* accI = (float*)suballoc((size_t)nq * D * sizeof(float));
    int2* row_se = (int2*)suballoc((size_t)N * sizeof(int2));
    int* cursor = (int*)alloc((size_t)NBF * sizeof(int));
    int* scur = (int*)alloc((size_t)SB_MAX * sizeof(int));

    const int2* idx2 = (const int2*)adj_indices;
    const int nChunksA1 = (int)((nnz + CHUNK - 1) / CHUNK);

    // ---- e0 (bf16) = concat(user_emb, item_emb) ----
    {
        long long total4 = (long long)N * (D / 4);
        long long nU4 = (long long)n_users * (D / 4);
        pack_e0<<<(int)((total4 + 255) / 256), 256, 0, stream>>>(
            (const float4*)user_emb, (const float4*)item_emb, (uint2*)ebf0, nU4, total4);
    }

    // ---- two-level radix scatter -> row-sorted fine bins ----
    hipMemsetAsync(scur, 0, (size_t)SB_MAX * sizeof(int), stream);
    hipMemsetAsync(cursor, 0, (size_t)NBF * sizeof(int), stream);
    scatter_super<<<nChunksA1, 256, 0, stream>>>(idx2, adj_data, scur, sbinned, nnz, nsup);
    scatter_fine<<<nsup * CPS, 256, 0, stream>>>(sbinned, scur, cursor, binned);
    bin_sort<<<NB, 256, 0, stream>>>(binned, cursor, row_se, N);

    // accU/accI alias sbinned -> init only after scatter_fine (stream-ordered)
    gather_init<<<nq, 64, 0, stream>>>(user_emb, item_emb, user_idx, item_idx, accU, accI);

    // ---- layers 1-2: full SpMM + query-row accumulation ----
    ushort* ebc = ebf0;
    ushort* ebn = ebf1;
    const int spmm_blocks = (N + 3) / 4;
    for (int layer = 0; layer < 2; ++layer) {
        spmm_bf16<<<spmm_blocks, 256, 0, stream>>>(binned, row_se, ebc, ebn, N);
        gather_acc<<<nq, 64, 0, stream>>>(ebn, user_idx, item_idx, accU, accI, n_users);
        ushort* t = ebc; ebc = ebn; ebn = t;
    }

    // ---- layer 3 fused: SpMM restricted to the 8192 query rows, f32 accumulate ----
    spmm_query<<<(2 * nq + 3) / 4, 256, 0, stream>>>(binned, row_se, ebc, user_idx, item_idx,
                                                     accU, accI, n_users, nq);

    final_dot<<<nq, 64, 0, stream>>>(accU, accI, out);
}